// Round 2
// baseline (281.863 us; speedup 1.0000x reference)
//
#include <hip/hip_runtime.h>

// ParallelLinear: out[b,t,o] = sum_i x[b,t,i] * W[t,o,i] + bias[t,o]
// B=512, T=1024, K=O=64, fp32 in/out.
//
// LDS-free MFMA design: both x ([b][t][k], k contiguous) and W ([t][o][k],
// k contiguous) feed mfma_f32_16x16x32_bf16 fragments directly from global:
// lane holds 8 consecutive k (32 B fp32 -> cvt to bf16x8 in-register).
//   A frag (X):  A[m][k], m = lane&15 (row), k = (lane>>4)*8 + j
//   B frag (W):  B[k][n], n = lane&15 (o-col), k = (lane>>4)*8 + j
//   C/D:         col = lane&15, row = (lane>>4)*4 + reg   [m89/m91 verified]
// One wave: 16 rows x 64 cols, K=64 -> 2 A-frags, 8 B-frags, 8 MFMAs.
// No LDS, no barriers. W[t] re-read by 32 waves -> L1/L2 hits.

#define T_DIM 1024
#define B_DIM 512

typedef __attribute__((ext_vector_type(8))) short bf16x8;
typedef __attribute__((ext_vector_type(4))) float f32x4;

__device__ inline short f2bf(float f) {
    union { float f; unsigned u; } v; v.f = f;
    unsigned r = v.u + 0x7FFF + ((v.u >> 16) & 1);   // round-to-nearest-even
    return (short)(r >> 16);
}

__global__ __launch_bounds__(256) void pl_mfma(
    const float* __restrict__ x,
    const float* __restrict__ W,
    const float* __restrict__ bias,
    float* __restrict__ out)
{
    const int t     = blockIdx.x >> 3;        // 0..1023
    const int chunk = blockIdx.x & 7;         // 0..7
    const int wave  = threadIdx.x >> 6;       // 0..3
    const int lane  = threadIdx.x & 63;
    const int m     = lane & 15;              // A row / B col / D col
    const int q     = lane >> 4;              // quad 0..3

    const int b0 = chunk * 64 + wave * 16;    // this wave's 16 rows

    // ---- A fragments: x[b0+m][t][kc*32 + q*8 .. +7], kc = 0,1 ----
    bf16x8 afrag[2];
    {
        const float* xp = x + ((size_t)(b0 + m) * T_DIM + t) * 64 + q * 8;
        #pragma unroll
        for (int kc = 0; kc < 2; ++kc) {
            f32x4 lo = *(const f32x4*)(xp + kc * 32);
            f32x4 hi = *(const f32x4*)(xp + kc * 32 + 4);
            #pragma unroll
            for (int j = 0; j < 4; ++j) {
                afrag[kc][j]     = f2bf(lo[j]);
                afrag[kc][j + 4] = f2bf(hi[j]);
            }
        }
    }

    // ---- 4 output tiles (o0 = 0,16,32,48), each K=64 via 2 MFMAs ----
    f32x4 acc[4];
    const float* wbase = W + (size_t)t * (64 * 64) + (size_t)m * 64 + q * 8;
    #pragma unroll
    for (int ot = 0; ot < 4; ++ot) {
        f32x4 c = {0.f, 0.f, 0.f, 0.f};
        #pragma unroll
        for (int kc = 0; kc < 2; ++kc) {
            // B[k][n] = W[t][o0+n][k]; lane n=m reads row o0+m, 8 consecutive k
            const float* wp = wbase + (size_t)ot * (16 * 64) + kc * 32;
            f32x4 lo = *(const f32x4*)wp;
            f32x4 hi = *(const f32x4*)(wp + 4);
            bf16x8 bfrag;
            #pragma unroll
            for (int j = 0; j < 4; ++j) {
                bfrag[j]     = f2bf(lo[j]);
                bfrag[j + 4] = f2bf(hi[j]);
            }
            c = __builtin_amdgcn_mfma_f32_16x16x32_bf16(afrag[kc], bfrag, c, 0, 0, 0);
        }
        acc[ot] = c;
    }

    // ---- epilogue: + bias, scatter-store (4 rows x 64B contiguous segments) ----
    #pragma unroll
    for (int ot = 0; ot < 4; ++ot) {
        float bv = bias[(size_t)t * 64 + ot * 16 + m];
        #pragma unroll
        for (int r = 0; r < 4; ++r) {
            int b = b0 + q * 4 + r;
            out[((size_t)b * T_DIM + t) * 64 + ot * 16 + m] = acc[ot][r] + bv;
        }
    }
}

extern "C" void kernel_launch(void* const* d_in, const int* in_sizes, int n_in,
                              void* d_out, int out_size, void* d_ws, size_t ws_size,
                              hipStream_t stream) {
    const float* x    = (const float*)d_in[0];
    const float* W    = (const float*)d_in[1];
    const float* bias = (const float*)d_in[2];
    float* out        = (float*)d_out;

    dim3 grid(T_DIM * (B_DIM / 64));   // 8192 blocks, 4 independent waves each
    dim3 block(256);
    pl_mfma<<<grid, block, 0, stream>>>(x, W, bias, out);
}

// Round 3
// 260.795 us; speedup vs baseline: 1.0808x; 1.0808x over previous
//
#include <hip/hip_runtime.h>

// ParallelLinear: out[b,t,o] = sum_i x[b,t,i] * W[t,o,i] + bias[t,o]
// B=512, T=1024, K=O=64, fp32 in/out.
//
// R3: coalesced float4 global->LDS staging (bf16, pitch 72 = 144 B rows so
// ds_read_b128 fragment reads are bank-conflict-free: group (9m+q)%8 uniform)
// + mfma_f32_16x16x32_bf16 compute (12 b128 reads + 16 MFMAs per wave).
// Block = 256 thr (4 waves), one t, 128 rows of b. Grid = 1024*4.
//   A frag: A[m][k], m=lane&15, k=q*8+j        (q = lane>>4)
//   B frag: B[k][n], n=lane&15, k=q*8+j  (= W[o=n][k], row-major, no transpose)
//   C/D:    col=lane&15, row=q*4+reg           [verified R2]

#define T_DIM 1024
#define B_DIM 512
#define PITCH 72   // bf16 elements per LDS row (144 B = 9 x 16 B groups)

typedef __attribute__((ext_vector_type(8))) short bf16x8;
typedef __attribute__((ext_vector_type(4))) short s16x4;
typedef __attribute__((ext_vector_type(4))) float f32x4;

__device__ inline short f2bf(float f) {
    union { float f; unsigned u; } v; v.f = f;
    unsigned r = v.u + 0x7FFF + ((v.u >> 16) & 1);   // RNE
    return (short)(r >> 16);
}

__global__ __launch_bounds__(256) void pl_mfma_lds(
    const float* __restrict__ x,
    const float* __restrict__ W,
    const float* __restrict__ bias,
    float* __restrict__ out)
{
    __shared__ short Xs[128 * PITCH];   // 18432 B
    __shared__ short Ws[64 * PITCH];    //  9216 B

    const int t     = blockIdx.x >> 2;      // 0..1023
    const int chunk = blockIdx.x & 3;       // 0..3
    const int b0    = chunk * 128;
    const int tid   = threadIdx.x;

    // ---- stage x tile: 128 rows x 64 f32, coalesced float4, cvt->bf16 ----
    #pragma unroll
    for (int j = 0; j < 8; ++j) {
        int fidx = j * 256 + tid;           // float4 index 0..2047
        int row  = fidx >> 4;               // 0..127
        int kq   = fidx & 15;               // 0..15 -> k0 = kq*4
        f32x4 v = *(const f32x4*)(x + ((size_t)(b0 + row) * T_DIM + t) * 64 + kq * 4);
        s16x4 h = { f2bf(v.x), f2bf(v.y), f2bf(v.z), f2bf(v.w) };
        *(s16x4*)&Xs[row * PITCH + kq * 4] = h;
    }

    // ---- stage W[t]: 64 rows x 64 f32, row-major (o,k), cvt->bf16 ----
    {
        const float* Wg = W + (size_t)t * (64 * 64);
        #pragma unroll
        for (int j = 0; j < 4; ++j) {
            int fidx = j * 256 + tid;       // 0..1023
            int o    = fidx >> 4;           // 0..63
            int kq   = fidx & 15;
            f32x4 v = *(const f32x4*)(Wg + (size_t)o * 64 + kq * 4);
            s16x4 h = { f2bf(v.x), f2bf(v.y), f2bf(v.z), f2bf(v.w) };
            *(s16x4*)&Ws[o * PITCH + kq * 4] = h;
        }
    }

    __syncthreads();

    // ---- compute: wave w -> rows w*32..w*32+31 (2 m-tiles), all 64 cols ----
    const int w    = tid >> 6;
    const int lane = tid & 63;
    const int m    = lane & 15;
    const int q    = lane >> 4;

    bf16x8 afr[2][2];   // [mtile][kc]
    #pragma unroll
    for (int mt = 0; mt < 2; ++mt)
        #pragma unroll
        for (int kc = 0; kc < 2; ++kc)
            afr[mt][kc] = *(const bf16x8*)&Xs[(w * 32 + mt * 16 + m) * PITCH + kc * 32 + q * 8];

    f32x4 acc[2][4] = {};
    #pragma unroll
    for (int ot = 0; ot < 4; ++ot) {
        #pragma unroll
        for (int kc = 0; kc < 2; ++kc) {
            bf16x8 bfr = *(const bf16x8*)&Ws[(ot * 16 + m) * PITCH + kc * 32 + q * 8];
            acc[0][ot] = __builtin_amdgcn_mfma_f32_16x16x32_bf16(afr[0][kc], bfr, acc[0][ot], 0, 0, 0);
            acc[1][ot] = __builtin_amdgcn_mfma_f32_16x16x32_bf16(afr[1][kc], bfr, acc[1][ot], 0, 0, 0);
        }
    }

    // ---- epilogue: + bias, store (C/D: col=m, row=q*4+r) ----
    #pragma unroll
    for (int ot = 0; ot < 4; ++ot) {
        float bv = bias[(size_t)t * 64 + ot * 16 + m];
        #pragma unroll
        for (int mt = 0; mt < 2; ++mt) {
            #pragma unroll
            for (int r = 0; r < 4; ++r) {
                int b = b0 + w * 32 + mt * 16 + q * 4 + r;
                out[((size_t)b * T_DIM + t) * 64 + ot * 16 + m] = acc[mt][ot][r] + bv;
            }
        }
    }
}

extern "C" void kernel_launch(void* const* d_in, const int* in_sizes, int n_in,
                              void* d_out, int out_size, void* d_ws, size_t ws_size,
                              hipStream_t stream) {
    const float* x    = (const float*)d_in[0];
    const float* W    = (const float*)d_in[1];
    const float* bias = (const float*)d_in[2];
    float* out        = (float*)d_out;

    dim3 grid(T_DIM * (B_DIM / 128));   // 4096 blocks
    dim3 block(256);
    pl_mfma_lds<<<grid, block, 0, stream>>>(x, W, bias, out);
}